// Round 2
// baseline (254.884 us; speedup 1.0000x reference)
//
#include <hip/hip_runtime.h>

// Embedding gather: out[token, :] = kernel[idx[token], :]  (all f32)
// TOKENS = 262144, EMBED = 256 (1 KiB/row), VOCAB = 256 (table 256 KiB,
// L2-resident). Output = 256 MiB HBM writes -> ~41 us floor at the
// fill-demonstrated 6.6 TB/s. Harness dur_us includes a ~164 us 1 GiB
// poison fill; kernel-only is dur_us - ~164.
//
// R6 post-mortem: double-buffered reg pipeline was NULL (251 vs 254 us).
// Cause: CDNA counts stores in vmcnt and store-source VGPRs can't be
// reused until the store completes; reloading bufA immediately after
// storing it forces s_waitcnt vmcnt(0) -- a full drain each half-iter.
//
// R7: NO register reuse inside a wave. 16 rows/wave, one distinct uint4
// per row: issue all 16 row loads, then store in order. In-order vmcnt
// means each store waits only vmcnt(15) (its own load retired) -- never a
// drain; stores at wave end are fire-and-forget. ~84 VGPR -> 6 waves/SIMD,
// ~24 waves/CU, each with ~16 vmem ops in flight. 16384 waves / 4096 blocks.

#define EMBED 256
#define CHUNKS_PER_ROW (EMBED / 4)      // 64 x 16B chunks per 1 KiB row
#define ROWS_PER_WAVE 16
#define WAVES_PER_BLOCK 4

typedef unsigned int u32x4 __attribute__((ext_vector_type(4)));

__global__ __launch_bounds__(256) void embedding_gather_kernel(
    const int* __restrict__ indices,          // [TOKENS] int32
    const u32x4* __restrict__ table,          // [VOCAB*EMBED] f32 as 16B chunks
    u32x4* __restrict__ out,                  // [TOKENS*EMBED] f32 as 16B chunks
    int tokens)
{
    const int lane    = threadIdx.x & 63;
    const int wave_id = blockIdx.x * WAVES_PER_BLOCK + (threadIdx.x >> 6);
    const long row_base = (long)wave_id * ROWS_PER_WAVE;
    if (row_base >= tokens) return;

    // One coalesced load: lane l (l < 16) holds the index for row row_base+l.
    int my_idx = 0;
    if (lane < ROWS_PER_WAVE && row_base + lane < tokens)
        my_idx = indices[row_base + lane];

    const u32x4* __restrict__ tb  = table + lane;                        // + lane*16B
    u32x4* __restrict__       dst = out + (size_t)row_base * CHUNKS_PER_ROW + lane;

    const long rem  = tokens - row_base;
    const int  rows = rem < ROWS_PER_WAVE ? (int)rem : ROWS_PER_WAVE;

    if (rows == ROWS_PER_WAVE) {
        // Distinct registers per row: no WAR hazard, no vmcnt(0) drain.
        u32x4 buf[ROWS_PER_WAVE];

        #pragma unroll
        for (int g = 0; g < ROWS_PER_WAVE; ++g) {
            const int idx = __builtin_amdgcn_readlane(my_idx, g);   // SGPR base
            buf[g] = tb[(size_t)idx * CHUNKS_PER_ROW];
        }
        #pragma unroll
        for (int g = 0; g < ROWS_PER_WAVE; ++g)
            dst[(size_t)g * CHUNKS_PER_ROW] = buf[g];
    } else {
        // Partial tail wave (not hit at 262144 tokens, kept for safety).
        for (int i = 0; i < rows; ++i) {
            const int idx = __builtin_amdgcn_readlane(my_idx, i);
            dst[(size_t)i * CHUNKS_PER_ROW] = tb[(size_t)idx * CHUNKS_PER_ROW];
        }
    }
}

extern "C" void kernel_launch(void* const* d_in, const int* in_sizes, int n_in,
                              void* d_out, int out_size, void* d_ws, size_t ws_size,
                              hipStream_t stream) {
    const int*   indices = (const int*)d_in[0];    // [262144] int32
    const u32x4* table   = (const u32x4*)d_in[1];  // [256*256] f32 as 16B chunks
    u32x4*       out     = (u32x4*)d_out;          // [262144*256] f32 as 16B chunks

    const int tokens = in_sizes[0];                                       // 262144
    const int waves  = (tokens + ROWS_PER_WAVE - 1) / ROWS_PER_WAVE;      // 16384
    const int blocks = (waves + WAVES_PER_BLOCK - 1) / WAVES_PER_BLOCK;   // 4096

    embedding_gather_kernel<<<blocks, 256, 0, stream>>>(indices, table, out, tokens);
}